// Round 8
// baseline (301.198 us; speedup 1.0000x reference)
//
#include <hip/hip_runtime.h>
#include <math.h>

#define NTOT   65536
#define DDIM   256
#define BATCH  2048
#define NPREV  (NTOT - BATCH)   // 63488

#define NC_P 31
#define CHUNK_P 2048            // 31 * 2048 = 63488
#define NC_R 8
#define CHUNK_R 256             // 8 * 256 = 2048

#define INF_F 3.402823466e+38f
#define SWZ(r) ((((r) & 3)) ^ ((((r) >> 2) & 3)))

typedef float  f32x4  __attribute__((ext_vector_type(4)));
typedef float  f32x16 __attribute__((ext_vector_type(16)));
typedef _Float16 half8 __attribute__((ext_vector_type(8)));

#define TILE_HALVES 65536   // per 128-row tile image
#define KB_HALVES   8192    // per kb block within a tile

#define SCHED_FENCE() __builtin_amdgcn_sched_barrier(0)
#define RAW_BARRIER() do { SCHED_FENCE(); __builtin_amdgcn_s_barrier(); SCHED_FENCE(); } while (0)
#define VMCNT6()  do { asm volatile("s_waitcnt vmcnt(6)" ::: "memory"); SCHED_FENCE(); } while (0)
#define VMCNT0()  do { asm volatile("s_waitcnt vmcnt(0)" ::: "memory"); SCHED_FENCE(); } while (0)
#define LGKM0()   do { asm volatile("s_waitcnt lgkmcnt(0)" ::: "memory"); SCHED_FENCE(); } while (0)

// ---------------- row norms (fallback path) ----------------
__global__ void lp_norms(const float* __restrict__ lib, float* __restrict__ ln) {
    const int row  = blockIdx.x * 4 + (threadIdx.x >> 6);
    const int lane = threadIdx.x & 63;
    const float4 v = reinterpret_cast<const float4*>(lib + (size_t)row * DDIM)[lane];
    float s = v.x * v.x + v.y * v.y + v.z * v.z + v.w * v.w;
#pragma unroll
    for (int off = 32; off > 0; off >>= 1) s += __shfl_down(s, off);
    if (lane == 0) ln[row] = s;
}

// fp16 split with x256 scaling
__device__ __forceinline__ void cvt_split(const f32x4 a, const f32x4 b,
                                          half8& h, half8& l) {
    float v[8] = {a[0], a[1], a[2], a[3], b[0], b[1], b[2], b[3]};
#pragma unroll
    for (int j = 0; j < 8; ++j) {
        const float s = v[j] * 256.0f;
        const _Float16 hh = (_Float16)s;
        const _Float16 ll = (_Float16)(s - (float)hh);
        h[j] = hh; l[j] = ll;
    }
}

// ---------------- pre-split fp32 -> fp16 hi/lo, 32x32-fragment-linear -------
__global__ void lp_split32(const float* __restrict__ src, _Float16* __restrict__ dst,
                           float* __restrict__ ln) {
    const int tile = blockIdx.x;
    const int t    = threadIdx.x;
    const int rg   = t >> 6;
    const int l    = t & 63;
    const int row  = rg * 32 + (l & 31);
    const int k8   = l >> 5;
    const float* srcR = src + (size_t)tile * 128 * DDIM + (size_t)row * DDIM;
    _Float16*    dstT = dst + (size_t)tile * TILE_HALVES;

    float nsum = 0.f;
#pragma unroll
    for (int kb = 0; kb < 8; ++kb) {
#pragma unroll
        for (int kk = 0; kk < 2; ++kk) {
            const float* p = srcR + kb * 32 + kk * 16 + k8 * 8;
            const f32x4 a = *reinterpret_cast<const f32x4*>(p);
            const f32x4 b = *reinterpret_cast<const f32x4*>(p + 4);
            half8 h, lo; cvt_split(a, b, h, lo);
            const size_t off = ((size_t)(((kb * 2 + 0) * 4 + rg) * 2 + kk) * 64 + l) * 8;
            *reinterpret_cast<half8*>(dstT + off)        = h;   // hl=0
            *reinterpret_cast<half8*>(dstT + off + 4096) = lo;  // hl=1
            nsum += a[0]*a[0] + a[1]*a[1] + a[2]*a[2] + a[3]*a[3]
                  + b[0]*b[0] + b[1]*b[1] + b[2]*b[2] + b[3]*b[3];
        }
    }
    nsum += __shfl_xor(nsum, 32);
    if (ln != nullptr && k8 == 0) ln[(size_t)tile * 128 + row] = nsum;
}

// ---------------- async 8KB stage: 512 threads x 16B, linear ----------------
__device__ __forceinline__ void stage8(_Float16* lds, const _Float16* g, int t) {
    __builtin_amdgcn_global_load_lds(
        (const __attribute__((address_space(1))) void*)(g + (size_t)t * 8),
        (__attribute__((address_space(3))) void*)(lds + (size_t)(t >> 6) * 512),
        16, 0, 0);
}

// ---------------- MFMA NN: 256x128 tile, 8 waves, 4-phase interleave --------
__global__ __launch_bounds__(512, 2)
void lp_nn_mfma6(const _Float16* __restrict__ Qs, const _Float16* __restrict__ Ls,
                 const float* __restrict__ ln, int chunkRows,
                 float* __restrict__ pscore, int* __restrict__ pidx, int nchunks)
{
    __shared__ _Float16 B0[24576];   // A: 16384 (two 128-row Q tiles), B: 8192
    __shared__ _Float16 B1[24576];
    __shared__ float lnLds[2048];
    __shared__ float xk[2][256];
    __shared__ int   xi[2][256];

    const int nwg  = 8 * nchunks;
    const int hid  = blockIdx.x;
    const int work = (hid & 7) * (nwg >> 3) + (hid >> 3);  // XCD-contiguous
    const int bx   = work & 7;      // query tile (256 rows)
    const int by   = work >> 3;     // lib chunk

    const int t    = threadIdx.x;
    const int lane = t & 63;
    const int wid  = t >> 6;        // 0..7
    const int wq   = wid >> 1;      // 0..3 : q-rows [wq*64, wq*64+64)
    const int wl   = wid & 1;       // 0..1 : l-cols [wl*64, wl*64+64)
    const int col  = lane & 31, hi = lane >> 5;
    const int chunkBase = by * chunkRows;

    const _Float16* Qt    = Qs + (size_t)(bx * 2) * TILE_HALVES;
    const _Float16* Lbase = Ls + (size_t)(chunkBase >> 7) * TILE_HALVES;
    const int NSTEP = (chunkRows >> 7) * 8;

    // fragment base offsets (halves) within a buffer
    int aB[2], bB[2];
#pragma unroll
    for (int mf = 0; mf < 2; ++mf) {
        const int ql = wq * 64 + mf * 32;
        aB[mf] = (ql >> 7) * 8192 + ((ql >> 5) & 3) * 1024 + lane * 8;
    }
#pragma unroll
    for (int nf = 0; nf < 2; ++nf)
        bB[nf] = 16384 + (wl * 2 + nf) * 1024 + lane * 8;

    float bkey[2][16];
    int   bidxr[2][16];
    f32x16 acc[2][2];
#pragma unroll
    for (int mf = 0; mf < 2; ++mf) {
#pragma unroll
        for (int r = 0; r < 16; ++r) { bkey[mf][r] = INF_F; bidxr[mf][r] = 0x7fffffff; }
#pragma unroll
        for (int nf = 0; nf < 2; ++nf) acc[mf][nf] = (f32x16)(0.f);
    }

    auto stage = [&](_Float16* dst, int s) {
        const int kb = s & 7, lt = s >> 3;
        const _Float16* Q0  = Qt + kb * KB_HALVES;
        const _Float16* Q1  = Qt + TILE_HALVES + kb * KB_HALVES;
        const _Float16* Lkb = Lbase + (size_t)lt * TILE_HALVES + kb * KB_HALVES;
        stage8(dst + 0,     Q0 + 0,    t);
        stage8(dst + 4096,  Q0 + 4096, t);
        stage8(dst + 8192,  Q1 + 0,    t);
        stage8(dst + 12288, Q1 + 4096, t);
        stage8(dst + 16384, Lkb + 0,    t);
        stage8(dst + 20480, Lkb + 4096, t);
    };

    auto fold = [&](int lt) {
#pragma unroll
        for (int nf = 0; nf < 2; ++nf) {
            const int lrow = lt * 128 + wl * 64 + nf * 32 + col;
            const float lnv = lnLds[lrow] * 65536.0f;
            const int gidx = chunkBase + lrow;
#pragma unroll
            for (int mf = 0; mf < 2; ++mf)
#pragma unroll
                for (int r = 0; r < 16; ++r) {
                    const float key = fmaf(-2.f, acc[mf][nf][r], lnv);
                    if (key < bkey[mf][r] || (key == bkey[mf][r] && gidx < bidxr[mf][r])) {
                        bkey[mf][r] = key; bidxr[mf][r] = gidx;
                    }
                    acc[mf][nf][r] = 0.f;
                }
        }
    };

    // 4 phases per step: (kk,nf) ∈ {(0,0),(0,1),(1,0),(1,1)}
    // phase = {ds_read subtile ; barrier ; lgkmcnt(0) ; setprio(1) 6xMFMA setprio(0)}
    auto step = [&](_Float16* buf, int s) {
        if (s + 1 < NSTEP) VMCNT6(); else VMCNT0();   // stage(s) done; stage(s+1) in flight
        RAW_BARRIER();                                // publish all waves' stage(s)
        half8 a[2][2], bb[2];
#pragma unroll
        for (int kk = 0; kk < 2; ++kk) {
            // ---- phase (kk, nf=0): reads a(kk) + b(kk,0) ----
#pragma unroll
            for (int mf = 0; mf < 2; ++mf)
#pragma unroll
                for (int hl = 0; hl < 2; ++hl)
                    a[mf][hl] = *reinterpret_cast<const half8*>(buf + aB[mf] + hl * 4096 + kk * 512);
#pragma unroll
            for (int hl = 0; hl < 2; ++hl)
                bb[hl] = *reinterpret_cast<const half8*>(buf + bB[0] + hl * 4096 + kk * 512);
            RAW_BARRIER(); LGKM0();
            __builtin_amdgcn_s_setprio(1);
#pragma unroll
            for (int mf = 0; mf < 2; ++mf) {
                acc[mf][0] = __builtin_amdgcn_mfma_f32_32x32x16_f16(a[mf][0], bb[0], acc[mf][0], 0, 0, 0);
                acc[mf][0] = __builtin_amdgcn_mfma_f32_32x32x16_f16(a[mf][0], bb[1], acc[mf][0], 0, 0, 0);
                acc[mf][0] = __builtin_amdgcn_mfma_f32_32x32x16_f16(a[mf][1], bb[0], acc[mf][0], 0, 0, 0);
            }
            __builtin_amdgcn_s_setprio(0);
            // ---- phase (kk, nf=1): reads b(kk,1) ----
#pragma unroll
            for (int hl = 0; hl < 2; ++hl)
                bb[hl] = *reinterpret_cast<const half8*>(buf + bB[1] + hl * 4096 + kk * 512);
            RAW_BARRIER(); LGKM0();
            __builtin_amdgcn_s_setprio(1);
#pragma unroll
            for (int mf = 0; mf < 2; ++mf) {
                acc[mf][1] = __builtin_amdgcn_mfma_f32_32x32x16_f16(a[mf][0], bb[0], acc[mf][1], 0, 0, 0);
                acc[mf][1] = __builtin_amdgcn_mfma_f32_32x32x16_f16(a[mf][0], bb[1], acc[mf][1], 0, 0, 0);
                acc[mf][1] = __builtin_amdgcn_mfma_f32_32x32x16_f16(a[mf][1], bb[0], acc[mf][1], 0, 0, 0);
            }
            __builtin_amdgcn_s_setprio(0);
        }
        RAW_BARRIER();                         // all waves done reading buf (WAR)
        if (s + 2 < NSTEP) stage(buf, s + 2);  // restage freed buffer; wait at next step top
        if ((s & 7) == 7) fold(s >> 3);        // lib tile finished
    };

    // prologue: ln -> LDS, then two stages in flight
    for (int i = t; i < chunkRows; i += 512) lnLds[i] = ln[chunkBase + i];
    SCHED_FENCE();
    stage(B0, 0);
    stage(B1, 1);
    LGKM0();   // own lnLds ds_writes complete (published at first step barrier)

    for (int s = 0; s < NSTEP; s += 2) {
        step(B0, s);
        step(B1, s + 1);
    }

    // butterfly-reduce across the 32 C-columns
#pragma unroll
    for (int off = 1; off < 32; off <<= 1)
#pragma unroll
        for (int mf = 0; mf < 2; ++mf)
#pragma unroll
            for (int r = 0; r < 16; ++r) {
                const float ok = __shfl_xor(bkey[mf][r], off);
                const int   oi = __shfl_xor(bidxr[mf][r], off);
                if (ok < bkey[mf][r] || (ok == bkey[mf][r] && oi < bidxr[mf][r])) {
                    bkey[mf][r] = ok; bidxr[mf][r] = oi;
                }
            }
    // deposit per-row best; C row = (r&3) + 8*(r>>2) + 4*hi within 32-row tile
    if (col == 0)
#pragma unroll
        for (int mf = 0; mf < 2; ++mf)
#pragma unroll
            for (int r = 0; r < 16; ++r) {
                const int ql = wq * 64 + mf * 32 + (r & 3) + 8 * (r >> 2) + 4 * hi;
                xk[wl][ql] = bkey[mf][r];
                xi[wl][ql] = bidxr[mf][r];
            }
    __syncthreads();
    if (t < 256) {
        float bk = xk[0][t]; int bi = xi[0][t];
        const float k2 = xk[1][t]; const int i2 = xi[1][t];
        if (k2 < bk || (k2 == bk && i2 < bi)) { bk = k2; bi = i2; }
        const int q = bx * 256 + t;
        pscore[(size_t)q * nchunks + by] = bk;
        pidx  [(size_t)q * nchunks + by] = bi;
    }
}

// ---------------- fallback MFMA kernel (round-3, in-loop split) -------------
__global__ __launch_bounds__(256, 2)
void lp_nn_mfma_fb(const float* __restrict__ Q, const float* __restrict__ L,
                   const float* __restrict__ ln, int chunkRows,
                   float* __restrict__ pscore, int* __restrict__ pidx, int nchunks)
{
    __shared__ _Float16 Ah[128 * 32];
    __shared__ _Float16 Al[128 * 32];
    __shared__ _Float16 Bh[128 * 32];
    __shared__ _Float16 Bl[128 * 32];
    __shared__ float xk[2][128];
    __shared__ int   xi[2][128];

    const int t    = threadIdx.x;
    const int wid  = t >> 6, lane = t & 63;
    const int wq   = wid >> 1, wl = wid & 1;
    const int col  = lane & 15, rg = lane >> 4;
    const int qbase = blockIdx.x * 128;
    const int chunkBase = blockIdx.y * chunkRows;
    const int srow   = t >> 2;
    const int schunk = t & 3;

    float bkey[4][4];
    int   bidxr[4][4];
#pragma unroll
    for (int mf = 0; mf < 4; ++mf)
#pragma unroll
        for (int i = 0; i < 4; ++i) { bkey[mf][i] = INF_F; bidxr[mf][i] = 0x7fffffff; }

    for (int lt = 0; lt < chunkRows; lt += 128) {
        f32x4 acc[4][4];
#pragma unroll
        for (int mf = 0; mf < 4; ++mf)
#pragma unroll
            for (int nf = 0; nf < 4; ++nf) acc[mf][nf] = (f32x4)(0.f);

        for (int kb = 0; kb < DDIM; kb += 32) {
            __syncthreads();
#pragma unroll
            for (int sr = 0; sr < 2; ++sr) {
                const int r = srow + 64 * sr;
                const int s = schunk ^ SWZ(r);
                {
                    const float* src = Q + (size_t)(qbase + r) * DDIM + kb + schunk * 8;
                    const f32x4 a = *reinterpret_cast<const f32x4*>(src);
                    const f32x4 b = *reinterpret_cast<const f32x4*>(src + 4);
                    half8 h, l; cvt_split(a, b, h, l);
                    *reinterpret_cast<half8*>(&Ah[r * 32 + s * 8]) = h;
                    *reinterpret_cast<half8*>(&Al[r * 32 + s * 8]) = l;
                }
                {
                    const float* src = L + (size_t)(chunkBase + lt + r) * DDIM + kb + schunk * 8;
                    const f32x4 a = *reinterpret_cast<const f32x4*>(src);
                    const f32x4 b = *reinterpret_cast<const f32x4*>(src + 4);
                    half8 h, l; cvt_split(a, b, h, l);
                    *reinterpret_cast<half8*>(&Bh[r * 32 + s * 8]) = h;
                    *reinterpret_cast<half8*>(&Bl[r * 32 + s * 8]) = l;
                }
            }
            __syncthreads();

            half8 ah[4], al[4];
#pragma unroll
            for (int mf = 0; mf < 4; ++mf) {
                const int r = wq * 64 + mf * 16 + col;
                const int s = rg ^ SWZ(r);
                ah[mf] = *reinterpret_cast<const half8*>(&Ah[r * 32 + s * 8]);
                al[mf] = *reinterpret_cast<const half8*>(&Al[r * 32 + s * 8]);
            }
#pragma unroll
            for (int nf = 0; nf < 4; ++nf) {
                const int r = wl * 64 + nf * 16 + col;
                const int s = rg ^ SWZ(r);
                const half8 bh = *reinterpret_cast<const half8*>(&Bh[r * 32 + s * 8]);
                const half8 bl = *reinterpret_cast<const half8*>(&Bl[r * 32 + s * 8]);
#pragma unroll
                for (int mf = 0; mf < 4; ++mf) {
                    acc[mf][nf] = __builtin_amdgcn_mfma_f32_16x16x32_f16(ah[mf], bh, acc[mf][nf], 0, 0, 0);
                    acc[mf][nf] = __builtin_amdgcn_mfma_f32_16x16x32_f16(ah[mf], bl, acc[mf][nf], 0, 0, 0);
                    acc[mf][nf] = __builtin_amdgcn_mfma_f32_16x16x32_f16(al[mf], bh, acc[mf][nf], 0, 0, 0);
                }
            }
        }

#pragma unroll
        for (int nf = 0; nf < 4; ++nf) {
            const int gidx = chunkBase + lt + wl * 64 + nf * 16 + col;
            const float lnv = ln[gidx] * 65536.0f;
#pragma unroll
            for (int mf = 0; mf < 4; ++mf)
#pragma unroll
                for (int i = 0; i < 4; ++i) {
                    const float key = fmaf(-2.f, acc[mf][nf][i], lnv);
                    if (key < bkey[mf][i] || (key == bkey[mf][i] && gidx < bidxr[mf][i])) {
                        bkey[mf][i] = key; bidxr[mf][i] = gidx;
                    }
                }
        }
    }

#pragma unroll
    for (int off = 1; off < 16; off <<= 1)
#pragma unroll
        for (int mf = 0; mf < 4; ++mf)
#pragma unroll
            for (int i = 0; i < 4; ++i) {
                const float ok = __shfl_xor(bkey[mf][i], off);
                const int   oi = __shfl_xor(bidxr[mf][i], off);
                if (ok < bkey[mf][i] || (ok == bkey[mf][i] && oi < bidxr[mf][i])) {
                    bkey[mf][i] = ok; bidxr[mf][i] = oi;
                }
            }
    if (col == 0)
#pragma unroll
        for (int mf = 0; mf < 4; ++mf)
#pragma unroll
            for (int i = 0; i < 4; ++i) {
                const int ql = wq * 64 + mf * 16 + rg * 4 + i;
                xk[wl][ql] = bkey[mf][i];
                xi[wl][ql] = bidxr[mf][i];
            }
    __syncthreads();
    if (t < 128) {
        float bk = xk[0][t]; int bi = xi[0][t];
        const float k2 = xk[1][t]; const int i2 = xi[1][t];
        if (k2 < bk || (k2 == bk && i2 < bi)) { bk = k2; bi = i2; }
        const int q = qbase + t;
        pscore[(size_t)q * nchunks + blockIdx.y] = bk;
        pidx  [(size_t)q * nchunks + blockIdx.y] = bi;
    }
}

// ---------------- finalize: reduce partials, exact distances, value+grad ----
__global__ void lp_finalize(const float* __restrict__ Q,
                            const float* __restrict__ prevL,
                            const float* __restrict__ reachL,
                            const float* __restrict__ ps_p, const int* __restrict__ pi_p,
                            const float* __restrict__ ps_r, const int* __restrict__ pi_r,
                            float* __restrict__ out)
{
    const int q = blockIdx.x;
    const int lane = threadIdx.x;

    float k1 = (lane < NC_P) ? ps_p[(size_t)q * NC_P + lane] : INF_F;
    int   i1 = (lane < NC_P) ? pi_p[(size_t)q * NC_P + lane] : 0x7fffffff;
#pragma unroll
    for (int off = 32; off > 0; off >>= 1) {
        const float ok = __shfl_xor(k1, off);
        const int   oi = __shfl_xor(i1, off);
        if (ok < k1 || (ok == k1 && oi < i1)) { k1 = ok; i1 = oi; }
    }
    float k2 = (lane < NC_R) ? ps_r[(size_t)q * NC_R + lane] : INF_F;
    int   i2 = (lane < NC_R) ? pi_r[(size_t)q * NC_R + lane] : 0x7fffffff;
#pragma unroll
    for (int off = 32; off > 0; off >>= 1) {
        const float ok = __shfl_xor(k2, off);
        const int   oi = __shfl_xor(i2, off);
        if (ok < k2 || (ok == k2 && oi < i2)) { k2 = ok; i2 = oi; }
    }

    const float4 tv = reinterpret_cast<const float4*>(Q      + (size_t)q  * DDIM)[lane];
    const float4 e1 = reinterpret_cast<const float4*>(prevL  + (size_t)i1 * DDIM)[lane];
    const float4 e2 = reinterpret_cast<const float4*>(reachL + (size_t)i2 * DDIM)[lane];
    const float4 d1 = {tv.x - e1.x, tv.y - e1.y, tv.z - e1.z, tv.w - e1.w};
    const float4 d2 = {tv.x - e2.x, tv.y - e2.y, tv.z - e2.z, tv.w - e2.w};
    float s1 = d1.x * d1.x + d1.y * d1.y + d1.z * d1.z + d1.w * d1.w;
    float s2 = d2.x * d2.x + d2.y * d2.y + d2.z * d2.z + d2.w * d2.w;
#pragma unroll
    for (int off = 32; off > 0; off >>= 1) {
        s1 += __shfl_xor(s1, off);
        s2 += __shfl_xor(s2, off);
    }
    const float r1 = sqrtf(s1), r2 = sqrtf(s2);
    float4 g;
    g.x = d1.x / r1 - d2.x / r2;
    g.y = d1.y / r1 - d2.y / r2;
    g.z = d1.z / r1 - d2.z / r2;
    g.w = d1.w / r1 - d2.w / r2;
    reinterpret_cast<float4*>(out + BATCH + (size_t)q * DDIM)[lane] = g;
    if (lane == 0) out[q] = r1 - r2;
}

extern "C" void kernel_launch(void* const* d_in, const int* in_sizes, int n_in,
                              void* d_out, int out_size, void* d_ws, size_t ws_size,
                              hipStream_t stream) {
    const float* target_lib  = (const float*)d_in[0];
    const float* reached_lib = (const float*)d_in[1];
    const float* Qp     = target_lib  + (size_t)NPREV * DDIM;  // targets
    const float* prevL  = reached_lib;                          // prev
    const float* reachL = reached_lib + (size_t)NPREV * DDIM;  // reached

    float* ws     = (float*)d_ws;
    float* ln_all = ws;                                   // 65536 f
    float* ps_p   = ln_all + NTOT;                        // 2048*31 f
    float* ps_r   = ps_p + (size_t)BATCH * NC_P;          // 2048*8 f
    int*   pi_p   = (int*)(ps_r + (size_t)BATCH * NC_R);
    int*   pi_r   = pi_p + (size_t)BATCH * NC_P;
    _Float16* Qsp = (_Float16*)(pi_r + (size_t)BATCH * NC_R);          // 2 MB
    _Float16* Lsp = Qsp + (size_t)(BATCH / 128) * TILE_HALVES;         // 64 MB
    float* out    = (float*)d_out;

    const size_t need = (size_t)(NTOT + 2 * BATCH * (NC_P + NC_R)) * 4
                      + (size_t)(BATCH / 128 + NTOT / 128) * TILE_HALVES * 2;

    if (ws_size >= need) {
        lp_split32<<<NTOT / 128, 256, 0, stream>>>(reached_lib, Lsp, ln_all);
        lp_split32<<<BATCH / 128, 256, 0, stream>>>(Qp, Qsp, nullptr);
        lp_nn_mfma6<<<8 * NC_P, 512, 0, stream>>>(
            Qsp, Lsp, ln_all, CHUNK_P, ps_p, pi_p, NC_P);
        lp_nn_mfma6<<<8 * NC_R, 512, 0, stream>>>(
            Qsp, Lsp + (size_t)(NPREV / 128) * TILE_HALVES,
            ln_all + NPREV, CHUNK_R, ps_r, pi_r, NC_R);
    } else {
        lp_norms<<<NTOT / 4, 256, 0, stream>>>(reached_lib, ln_all);
        lp_nn_mfma_fb<<<dim3(BATCH / 128, NC_P), 256, 0, stream>>>(
            Qp, prevL, ln_all, CHUNK_P, ps_p, pi_p, NC_P);
        lp_nn_mfma_fb<<<dim3(BATCH / 128, NC_R), 256, 0, stream>>>(
            Qp, reachL, ln_all + NPREV, CHUNK_R, ps_r, pi_r, NC_R);
    }
    lp_finalize<<<BATCH, 64, 0, stream>>>(Qp, prevL, reachL, ps_p, pi_p, ps_r, pi_r, out);
}

// Round 9
// 254.579 us; speedup vs baseline: 1.1831x; 1.1831x over previous
//
#include <hip/hip_runtime.h>
#include <math.h>

#define NTOT   65536
#define DDIM   256
#define BATCH  2048
#define NPREV  (NTOT - BATCH)   // 63488

#define NC_P 16
#define CHUNK_P 3968            // 16 * 3968 = 63488 (31 tiles of 128)
#define NC_R 8
#define CHUNK_R 256             // 8 * 256 = 2048 (2 tiles of 128)

#define INF_F 3.402823466e+38f
#define SWZ(r) ((((r) & 3)) ^ ((((r) >> 2) & 3)))

typedef float  f32x4  __attribute__((ext_vector_type(4)));
typedef float  f32x16 __attribute__((ext_vector_type(16)));
typedef _Float16 half8 __attribute__((ext_vector_type(8)));

#define TILE_HALVES 65536   // per 128-row tile image (128r x 256k x hi/lo)
#define KB_HALVES   8192    // per kb block within a tile

#define SCHED_FENCE() __builtin_amdgcn_sched_barrier(0)
#define RAW_BARRIER() do { SCHED_FENCE(); __builtin_amdgcn_s_barrier(); SCHED_FENCE(); } while (0)
#define VMCNT2()  do { asm volatile("s_waitcnt vmcnt(2)" ::: "memory"); SCHED_FENCE(); } while (0)
#define VMCNT0()  do { asm volatile("s_waitcnt vmcnt(0)" ::: "memory"); SCHED_FENCE(); } while (0)

// ---------------- row norms (fallback path) ----------------
__global__ void lp_norms(const float* __restrict__ lib, float* __restrict__ ln) {
    const int row  = blockIdx.x * 4 + (threadIdx.x >> 6);
    const int lane = threadIdx.x & 63;
    const float4 v = reinterpret_cast<const float4*>(lib + (size_t)row * DDIM)[lane];
    float s = v.x * v.x + v.y * v.y + v.z * v.z + v.w * v.w;
#pragma unroll
    for (int off = 32; off > 0; off >>= 1) s += __shfl_down(s, off);
    if (lane == 0) ln[row] = s;
}

// fp16 split with x256 scaling
__device__ __forceinline__ void cvt_split(const f32x4 a, const f32x4 b,
                                          half8& h, half8& l) {
    float v[8] = {a[0], a[1], a[2], a[3], b[0], b[1], b[2], b[3]};
#pragma unroll
    for (int j = 0; j < 8; ++j) {
        const float s = v[j] * 256.0f;
        const _Float16 hh = (_Float16)s;
        const _Float16 ll = (_Float16)(s - (float)hh);
        h[j] = hh; l[j] = ll;
    }
}

// ---------------- pre-split fp32 -> fp16 hi/lo, 32x32-fragment-linear -------
__global__ void lp_split32(const float* __restrict__ src, _Float16* __restrict__ dst,
                           float* __restrict__ ln) {
    const int tile = blockIdx.x;
    const int t    = threadIdx.x;
    const int rg   = t >> 6;
    const int l    = t & 63;
    const int row  = rg * 32 + (l & 31);
    const int k8   = l >> 5;
    const float* srcR = src + (size_t)tile * 128 * DDIM + (size_t)row * DDIM;
    _Float16*    dstT = dst + (size_t)tile * TILE_HALVES;

    float nsum = 0.f;
#pragma unroll
    for (int kb = 0; kb < 8; ++kb) {
#pragma unroll
        for (int kk = 0; kk < 2; ++kk) {
            const float* p = srcR + kb * 32 + kk * 16 + k8 * 8;
            const f32x4 a = *reinterpret_cast<const f32x4*>(p);
            const f32x4 b = *reinterpret_cast<const f32x4*>(p + 4);
            half8 h, lo; cvt_split(a, b, h, lo);
            const size_t off = ((size_t)(((kb * 2 + 0) * 4 + rg) * 2 + kk) * 64 + l) * 8;
            *reinterpret_cast<half8*>(dstT + off)        = h;   // hl=0
            *reinterpret_cast<half8*>(dstT + off + 4096) = lo;  // hl=1
            nsum += a[0]*a[0] + a[1]*a[1] + a[2]*a[2] + a[3]*a[3]
                  + b[0]*b[0] + b[1]*b[1] + b[2]*b[2] + b[3]*b[3];
        }
    }
    nsum += __shfl_xor(nsum, 32);
    if (ln != nullptr && k8 == 0) ln[(size_t)tile * 128 + row] = nsum;
}

// ---------------- async 8KB stage: 512 threads x 16B, linear ----------------
__device__ __forceinline__ void stage8(_Float16* lds, const _Float16* g, int t) {
    __builtin_amdgcn_global_load_lds(
        (const __attribute__((address_space(1))) void*)(g + (size_t)t * 8),
        (__attribute__((address_space(3))) void*)(lds + (size_t)(t >> 6) * 512),
        16, 0, 0);
}

// ---------------- MFMA NN: Q-resident 128x128, counted-vmcnt, 8 waves -------
__global__ __launch_bounds__(512, 1)
void lp_nn_mfma7(const _Float16* __restrict__ Qs, const _Float16* __restrict__ Ls,
                 const float* __restrict__ ln, int chunkRows,
                 float* __restrict__ pscore, int* __restrict__ pidx, int nchunks)
{
    __shared__ _Float16 QB[65536];     // full Q tile image: 128 KB, staged once
    __shared__ _Float16 LB[2][8192];   // L kb double-buffer: 2 x 16 KB

    const int nwg  = 16 * nchunks;
    const int hid  = blockIdx.x;
    const int work = (hid & 7) * (nwg >> 3) + (hid >> 3);  // XCD-contiguous
    const int bx   = work & 15;     // query tile (128 rows)
    const int by   = work >> 4;     // lib chunk

    const int t    = threadIdx.x;
    const int lane = t & 63;
    const int wid  = t >> 6;        // 0..7
    const int wq   = wid >> 1;      // 0..3 : q-rows [wq*32, wq*32+32)
    const int wl   = wid & 1;       // 0..1 : l-cols [wl*64, wl*64+64)
    const int col  = lane & 31, hi = lane >> 5;
    const int chunkBase = by * chunkRows;
    const int NT   = chunkRows >> 7;

    const _Float16* Qt    = Qs + (size_t)bx * TILE_HALVES;
    const _Float16* Lbase = Ls + (size_t)(chunkBase >> 7) * TILE_HALVES;

    float bkey[16];
    int   bidx[16];
    f32x16 acc[2];
#pragma unroll
    for (int r = 0; r < 16; ++r) { bkey[r] = INF_F; bidx[r] = 0x7fffffff; }
    acc[0] = (f32x16)(0.f); acc[1] = (f32x16)(0.f);

    auto stageL = [&](_Float16* dst, int lt, int kb) {
        const _Float16* src = Lbase + (size_t)lt * TILE_HALVES + kb * KB_HALVES;
        stage8(dst,        src,        t);
        stage8(dst + 4096, src + 4096, t);
    };

    // prologue: whole Q image + first two L kb blocks
#pragma unroll
    for (int i = 0; i < 16; ++i) stage8(QB + i * 4096, Qt + i * 4096, t);
    stageL(LB[0], 0, 0);
    stageL(LB[1], 0, 1);

    float lnv0 = 0.f, lnv1 = 0.f;

    for (int lt = 0; lt < NT; ++lt) {
#pragma unroll
        for (int kb = 0; kb < 8; ++kb) {
            if (lt == NT - 1 && kb == 7) VMCNT0(); else VMCNT2();
            RAW_BARRIER();                       // stage(s) published to all waves
            if (kb == 0) {                       // prefetch ln for this tile's fold
                lnv0 = ln[chunkBase + lt * 128 + wl * 64 + col];
                lnv1 = ln[chunkBase + lt * 128 + wl * 64 + 32 + col];
            }
            // fragment loads (all conflict-free lane-linear b128)
            half8 av[2][2];   // [hl][kk]
#pragma unroll
            for (int hl = 0; hl < 2; ++hl)
#pragma unroll
                for (int kk = 0; kk < 2; ++kk)
                    av[hl][kk] = *reinterpret_cast<const half8*>(
                        QB + kb * 8192 + hl * 4096 + wq * 1024 + kk * 512 + lane * 8);
            half8 bv[2][2][2];   // [nf][hl][kk]
#pragma unroll
            for (int nf = 0; nf < 2; ++nf)
#pragma unroll
                for (int hl = 0; hl < 2; ++hl)
#pragma unroll
                    for (int kk = 0; kk < 2; ++kk)
                        bv[nf][hl][kk] = *reinterpret_cast<const half8*>(
                            LB[kb & 1] + hl * 4096 + (wl * 2 + nf) * 1024 + kk * 512 + lane * 8);
            __builtin_amdgcn_s_setprio(1);
#pragma unroll
            for (int nf = 0; nf < 2; ++nf)
#pragma unroll
                for (int kk = 0; kk < 2; ++kk) {
                    acc[nf] = __builtin_amdgcn_mfma_f32_32x32x16_f16(av[0][kk], bv[nf][0][kk], acc[nf], 0, 0, 0);
                    acc[nf] = __builtin_amdgcn_mfma_f32_32x32x16_f16(av[0][kk], bv[nf][1][kk], acc[nf], 0, 0, 0);
                    acc[nf] = __builtin_amdgcn_mfma_f32_32x32x16_f16(av[1][kk], bv[nf][0][kk], acc[nf], 0, 0, 0);
                }
            __builtin_amdgcn_s_setprio(0);
            RAW_BARRIER();                       // WAR: all waves done reading LB[kb&1]
            {
                const int s2lt = lt + ((kb + 2) >> 3);
                const int s2kb = (kb + 2) & 7;
                if (s2lt < NT) stageL(LB[kb & 1], s2lt, s2kb);
            }
            if (kb == 7) {                       // lib tile done: fold argmin
#pragma unroll
                for (int nf = 0; nf < 2; ++nf) {
                    const int gidx = chunkBase + lt * 128 + wl * 64 + nf * 32 + col;
                    const float lnvs = (nf ? lnv1 : lnv0) * 65536.0f;
#pragma unroll
                    for (int r = 0; r < 16; ++r) {
                        const float key = fmaf(-2.f, acc[nf][r], lnvs);
                        if (key < bkey[r] || (key == bkey[r] && gidx < bidx[r])) {
                            bkey[r] = key; bidx[r] = gidx;
                        }
                        acc[nf][r] = 0.f;
                    }
                }
            }
        }
    }

    // butterfly-reduce across the 32 C-columns (low 5 lane bits)
#pragma unroll
    for (int off = 1; off < 32; off <<= 1)
#pragma unroll
        for (int r = 0; r < 16; ++r) {
            const float ok = __shfl_xor(bkey[r], off);
            const int   oi = __shfl_xor(bidx[r], off);
            if (ok < bkey[r] || (ok == bkey[r] && oi < bidx[r])) {
                bkey[r] = ok; bidx[r] = oi;
            }
        }

    // cross-wave combine via LDS aliased onto LB (all LB reads are done)
    float* xk = (float*)&LB[0][0];      // [2][128] floats
    int*   xi = (int*)  &LB[0][1024];   // [2][128] ints (byte off 2048)
    if (col == 0)
#pragma unroll
        for (int r = 0; r < 16; ++r) {
            const int q = wq * 32 + (r & 3) + 8 * (r >> 2) + 4 * hi;
            xk[wl * 128 + q] = bkey[r];
            xi[wl * 128 + q] = bidx[r];
        }
    __syncthreads();
    if (t < 128) {
        float bk = xk[t]; int bi = xi[t];
        const float k2 = xk[128 + t]; const int i2 = xi[128 + t];
        if (k2 < bk || (k2 == bk && i2 < bi)) { bk = k2; bi = i2; }
        const int q = bx * 128 + t;
        pscore[(size_t)q * nchunks + by] = bk;
        pidx  [(size_t)q * nchunks + by] = bi;
    }
}

// ---------------- fallback MFMA kernel (round-3, in-loop split) -------------
__global__ __launch_bounds__(256, 2)
void lp_nn_mfma_fb(const float* __restrict__ Q, const float* __restrict__ L,
                   const float* __restrict__ ln, int chunkRows,
                   float* __restrict__ pscore, int* __restrict__ pidx, int nchunks)
{
    __shared__ _Float16 Ah[128 * 32];
    __shared__ _Float16 Al[128 * 32];
    __shared__ _Float16 Bh[128 * 32];
    __shared__ _Float16 Bl[128 * 32];
    __shared__ float xk[2][128];
    __shared__ int   xi[2][128];

    const int t    = threadIdx.x;
    const int wid  = t >> 6, lane = t & 63;
    const int wq   = wid >> 1, wl = wid & 1;
    const int col  = lane & 15, rg = lane >> 4;
    const int qbase = blockIdx.x * 128;
    const int chunkBase = blockIdx.y * chunkRows;
    const int srow   = t >> 2;
    const int schunk = t & 3;

    float bkey[4][4];
    int   bidxr[4][4];
#pragma unroll
    for (int mf = 0; mf < 4; ++mf)
#pragma unroll
        for (int i = 0; i < 4; ++i) { bkey[mf][i] = INF_F; bidxr[mf][i] = 0x7fffffff; }

    for (int lt = 0; lt < chunkRows; lt += 128) {
        f32x4 acc[4][4];
#pragma unroll
        for (int mf = 0; mf < 4; ++mf)
#pragma unroll
            for (int nf = 0; nf < 4; ++nf) acc[mf][nf] = (f32x4)(0.f);

        for (int kb = 0; kb < DDIM; kb += 32) {
            __syncthreads();
#pragma unroll
            for (int sr = 0; sr < 2; ++sr) {
                const int r = srow + 64 * sr;
                const int s = schunk ^ SWZ(r);
                {
                    const float* src = Q + (size_t)(qbase + r) * DDIM + kb + schunk * 8;
                    const f32x4 a = *reinterpret_cast<const f32x4*>(src);
                    const f32x4 b = *reinterpret_cast<const f32x4*>(src + 4);
                    half8 h, l; cvt_split(a, b, h, l);
                    *reinterpret_cast<half8*>(&Ah[r * 32 + s * 8]) = h;
                    *reinterpret_cast<half8*>(&Al[r * 32 + s * 8]) = l;
                }
                {
                    const float* src = L + (size_t)(chunkBase + lt + r) * DDIM + kb + schunk * 8;
                    const f32x4 a = *reinterpret_cast<const f32x4*>(src);
                    const f32x4 b = *reinterpret_cast<const f32x4*>(src + 4);
                    half8 h, l; cvt_split(a, b, h, l);
                    *reinterpret_cast<half8*>(&Bh[r * 32 + s * 8]) = h;
                    *reinterpret_cast<half8*>(&Bl[r * 32 + s * 8]) = l;
                }
            }
            __syncthreads();

            half8 ah[4], al[4];
#pragma unroll
            for (int mf = 0; mf < 4; ++mf) {
                const int r = wq * 64 + mf * 16 + col;
                const int s = rg ^ SWZ(r);
                ah[mf] = *reinterpret_cast<const half8*>(&Ah[r * 32 + s * 8]);
                al[mf] = *reinterpret_cast<const half8*>(&Al[r * 32 + s * 8]);
            }
#pragma unroll
            for (int nf = 0; nf < 4; ++nf) {
                const int r = wl * 64 + nf * 16 + col;
                const int s = rg ^ SWZ(r);
                const half8 bh = *reinterpret_cast<const half8*>(&Bh[r * 32 + s * 8]);
                const half8 bl = *reinterpret_cast<const half8*>(&Bl[r * 32 + s * 8]);
#pragma unroll
                for (int mf = 0; mf < 4; ++mf) {
                    acc[mf][nf] = __builtin_amdgcn_mfma_f32_16x16x32_f16(ah[mf], bh, acc[mf][nf], 0, 0, 0);
                    acc[mf][nf] = __builtin_amdgcn_mfma_f32_16x16x32_f16(ah[mf], bl, acc[mf][nf], 0, 0, 0);
                    acc[mf][nf] = __builtin_amdgcn_mfma_f32_16x16x32_f16(al[mf], bh, acc[mf][nf], 0, 0, 0);
                }
            }
        }

#pragma unroll
        for (int nf = 0; nf < 4; ++nf) {
            const int gidx = chunkBase + lt + wl * 64 + nf * 16 + col;
            const float lnv = ln[gidx] * 65536.0f;
#pragma unroll
            for (int mf = 0; mf < 4; ++mf)
#pragma unroll
                for (int i = 0; i < 4; ++i) {
                    const float key = fmaf(-2.f, acc[mf][nf][i], lnv);
                    if (key < bkey[mf][i] || (key == bkey[mf][i] && gidx < bidxr[mf][i])) {
                        bkey[mf][i] = key; bidxr[mf][i] = gidx;
                    }
                }
        }
    }

#pragma unroll
    for (int off = 1; off < 16; off <<= 1)
#pragma unroll
        for (int mf = 0; mf < 4; ++mf)
#pragma unroll
            for (int i = 0; i < 4; ++i) {
                const float ok = __shfl_xor(bkey[mf][i], off);
                const int   oi = __shfl_xor(bidxr[mf][i], off);
                if (ok < bkey[mf][i] || (ok == bkey[mf][i] && oi < bidxr[mf][i])) {
                    bkey[mf][i] = ok; bidxr[mf][i] = oi;
                }
            }
    if (col == 0)
#pragma unroll
        for (int mf = 0; mf < 4; ++mf)
#pragma unroll
            for (int i = 0; i < 4; ++i) {
                const int ql = wq * 64 + mf * 16 + rg * 4 + i;
                xk[wl][ql] = bkey[mf][i];
                xi[wl][ql] = bidxr[mf][i];
            }
    __syncthreads();
    if (t < 128) {
        float bk = xk[0][t]; int bi = xi[0][t];
        const float k2 = xk[1][t]; const int i2 = xi[1][t];
        if (k2 < bk || (k2 == bk && i2 < bi)) { bk = k2; bi = i2; }
        const int q = qbase + t;
        pscore[(size_t)q * nchunks + blockIdx.y] = bk;
        pidx  [(size_t)q * nchunks + blockIdx.y] = bi;
    }
}

// ---------------- finalize: reduce partials, exact distances, value+grad ----
__global__ void lp_finalize(const float* __restrict__ Q,
                            const float* __restrict__ prevL,
                            const float* __restrict__ reachL,
                            const float* __restrict__ ps_p, const int* __restrict__ pi_p,
                            const float* __restrict__ ps_r, const int* __restrict__ pi_r,
                            float* __restrict__ out)
{
    const int q = blockIdx.x;
    const int lane = threadIdx.x;

    float k1 = (lane < NC_P) ? ps_p[(size_t)q * NC_P + lane] : INF_F;
    int   i1 = (lane < NC_P) ? pi_p[(size_t)q * NC_P + lane] : 0x7fffffff;
#pragma unroll
    for (int off = 32; off > 0; off >>= 1) {
        const float ok = __shfl_xor(k1, off);
        const int   oi = __shfl_xor(i1, off);
        if (ok < k1 || (ok == k1 && oi < i1)) { k1 = ok; i1 = oi; }
    }
    float k2 = (lane < NC_R) ? ps_r[(size_t)q * NC_R + lane] : INF_F;
    int   i2 = (lane < NC_R) ? pi_r[(size_t)q * NC_R + lane] : 0x7fffffff;
#pragma unroll
    for (int off = 32; off > 0; off >>= 1) {
        const float ok = __shfl_xor(k2, off);
        const int   oi = __shfl_xor(i2, off);
        if (ok < k2 || (ok == k2 && oi < i2)) { k2 = ok; i2 = oi; }
    }

    const float4 tv = reinterpret_cast<const float4*>(Q      + (size_t)q  * DDIM)[lane];
    const float4 e1 = reinterpret_cast<const float4*>(prevL  + (size_t)i1 * DDIM)[lane];
    const float4 e2 = reinterpret_cast<const float4*>(reachL + (size_t)i2 * DDIM)[lane];
    const float4 d1 = {tv.x - e1.x, tv.y - e1.y, tv.z - e1.z, tv.w - e1.w};
    const float4 d2 = {tv.x - e2.x, tv.y - e2.y, tv.z - e2.z, tv.w - e2.w};
    float s1 = d1.x * d1.x + d1.y * d1.y + d1.z * d1.z + d1.w * d1.w;
    float s2 = d2.x * d2.x + d2.y * d2.y + d2.z * d2.z + d2.w * d2.w;
#pragma unroll
    for (int off = 32; off > 0; off >>= 1) {
        s1 += __shfl_xor(s1, off);
        s2 += __shfl_xor(s2, off);
    }
    const float r1 = sqrtf(s1), r2 = sqrtf(s2);
    float4 g;
    g.x = d1.x / r1 - d2.x / r2;
    g.y = d1.y / r1 - d2.y / r2;
    g.z = d1.z / r1 - d2.z / r2;
    g.w = d1.w / r1 - d2.w / r2;
    reinterpret_cast<float4*>(out + BATCH + (size_t)q * DDIM)[lane] = g;
    if (lane == 0) out[q] = r1 - r2;
}

extern "C" void kernel_launch(void* const* d_in, const int* in_sizes, int n_in,
                              void* d_out, int out_size, void* d_ws, size_t ws_size,
                              hipStream_t stream) {
    const float* target_lib  = (const float*)d_in[0];
    const float* reached_lib = (const float*)d_in[1];
    const float* Qp     = target_lib  + (size_t)NPREV * DDIM;  // targets
    const float* prevL  = reached_lib;                          // prev
    const float* reachL = reached_lib + (size_t)NPREV * DDIM;  // reached

    float* ws     = (float*)d_ws;
    float* ln_all = ws;                                   // 65536 f
    float* ps_p   = ln_all + NTOT;                        // 2048*16 f
    float* ps_r   = ps_p + (size_t)BATCH * NC_P;          // 2048*8 f
    int*   pi_p   = (int*)(ps_r + (size_t)BATCH * NC_R);
    int*   pi_r   = pi_p + (size_t)BATCH * NC_P;
    _Float16* Qsp = (_Float16*)(pi_r + (size_t)BATCH * NC_R);          // 2 MB
    _Float16* Lsp = Qsp + (size_t)(BATCH / 128) * TILE_HALVES;         // 64 MB
    float* out    = (float*)d_out;

    const size_t need = (size_t)(NTOT + 2 * BATCH * (NC_P + NC_R)) * 4
                      + (size_t)(BATCH / 128 + NTOT / 128) * TILE_HALVES * 2;

    if (ws_size >= need) {
        lp_split32<<<NTOT / 128, 256, 0, stream>>>(reached_lib, Lsp, ln_all);
        lp_split32<<<BATCH / 128, 256, 0, stream>>>(Qp, Qsp, nullptr);
        lp_nn_mfma7<<<16 * NC_P, 512, 0, stream>>>(
            Qsp, Lsp, ln_all, CHUNK_P, ps_p, pi_p, NC_P);
        lp_nn_mfma7<<<16 * NC_R, 512, 0, stream>>>(
            Qsp, Lsp + (size_t)(NPREV / 128) * TILE_HALVES,
            ln_all + NPREV, CHUNK_R, ps_r, pi_r, NC_R);
    } else {
        lp_norms<<<NTOT / 4, 256, 0, stream>>>(reached_lib, ln_all);
        lp_nn_mfma_fb<<<dim3(BATCH / 128, 31), 256, 0, stream>>>(
            Qp, prevL, ln_all, 2048, ps_p, pi_p, 31);
        lp_nn_mfma_fb<<<dim3(BATCH / 128, 16), 256, 0, stream>>>(
            Qp, reachL, ln_all + NPREV, 128, ps_r, pi_r, 16);
    }
    lp_finalize<<<BATCH, 64, 0, stream>>>(Qp, prevL, reachL, ps_p, pi_p, ps_r, pi_r, out);
}